// Round 1
// baseline (233.566 us; speedup 1.0000x reference)
//
#include <hip/hip_runtime.h>
#include <math.h>

#define N_AA    20
#define NATOM   15
#define D_FEAT  128
#define TM      32
#define FSTRIDE 88     // 48 coord (45 + 3 zero pad) + 40 dihedral (39 + 1 zero pad)
#define W1_N    256
#define ROW_COORD 128
#define ROW_DIH   1028
#define ROW_CHAIN 1067

// ---------------- tables: aaT[g][j] = aa_emb[g] @ W1[0:128], chT[c][j] = chain_emb[c] @ W1[1067:1195]
__global__ __launch_bounds__(256) void tables_kernel(
    const float* __restrict__ aa_emb, const float* __restrict__ chain_emb,
    const float* __restrict__ W1, float* __restrict__ aaT, float* __restrict__ chT)
{
    const int t = threadIdx.x;
    const int b = blockIdx.x;
    if (b < N_AA) {
        const float* e = aa_emb + b * D_FEAT;
        float acc = 0.f;
        for (int k = 0; k < D_FEAT; ++k)
            acc += e[k] * W1[(size_t)k * W1_N + t];
        aaT[b * W1_N + t] = acc;
    } else {
        const int c = b - N_AA;
        const float* e = chain_emb + c * D_FEAT;
        float acc = 0.f;
        for (int k = 0; k < D_FEAT; ++k)
            acc += e[k] * W1[(size_t)(ROW_CHAIN + k) * W1_N + t];
        chT[c * W1_N + t] = acc;
    }
}

__device__ __forceinline__ float4 relu4(float4 v) {
    float4 o;
    o.x = fmaxf(v.x, 0.f); o.y = fmaxf(v.y, 0.f);
    o.z = fmaxf(v.z, 0.f); o.w = fmaxf(v.w, 0.f);
    return o;
}

// ---------------- fused: features + 4-layer MLP, 32 rows per block
__global__ __launch_bounds__(256) void fused_kernel(
    const int* __restrict__ seq, const float* __restrict__ xyz,
    const float* __restrict__ dihedrals, const int* __restrict__ chain_idx,
    const float* __restrict__ orientation,
    const float* __restrict__ W1, const float* __restrict__ b1,
    const float* __restrict__ W2, const float* __restrict__ b2,
    const float* __restrict__ W3, const float* __restrict__ b3,
    const float* __restrict__ W4, const float* __restrict__ b4,
    const float* __restrict__ aaT, const float* __restrict__ chT,
    float* __restrict__ out)
{
    __shared__ float feat[TM][FSTRIDE];
    __shared__ float h1[TM][256];     // h3 (32x128) aliases this after layer 2
    __shared__ float h2[TM][128];
    __shared__ int   s_seq[TM];
    __shared__ int   s_chain[TM];

    const int t = threadIdx.x;
    const int row0 = blockIdx.x * TM;

    if (t < TM) {
        s_seq[t]   = seq[row0 + t];
        s_chain[t] = chain_idx[row0 + t];
        feat[t][45] = 0.f; feat[t][46] = 0.f; feat[t][47] = 0.f;  // coord pad
        feat[t][87] = 0.f;                                        // dihedral pad
    }

    // ---- coord features: xyz_local = O^T (xyz - CA) ----
    for (int p = t; p < TM * NATOM; p += 256) {
        const int r = p / NATOM, a = p % NATOM;
        const float* xr = xyz + (size_t)(row0 + r) * (NATOM * 3);
        const float cax = xr[3], cay = xr[4], caz = xr[5];   // CA_IDX = 1
        const float rx = xr[a*3+0] - cax;
        const float ry = xr[a*3+1] - cay;
        const float rz = xr[a*3+2] - caz;
        const float* O = orientation + (size_t)(row0 + r) * 9;
        feat[r][a*3+0] = O[0]*rx + O[3]*ry + O[6]*rz;
        feat[r][a*3+1] = O[1]*rx + O[4]*ry + O[7]*rz;
        feat[r][a*3+2] = O[2]*rx + O[5]*ry + O[8]*rz;
    }

    // ---- dihedral angular encoding: [x, sin(f*x)x6, cos(f*x)x6], f = {1,2,3,1,0.5,1/3} ----
    if (t < TM * 3) {
        const int r = t / 3, d = t % 3;
        const float x = dihedrals[(size_t)(row0 + r) * 3 + d];
        float* f = &feat[r][48 + d * 13];
        const float F3 = (float)(1.0 / 3.0);
        f[0]  = x;
        f[1]  = sinf(1.0f * x); f[2]  = sinf(2.0f * x); f[3]  = sinf(3.0f * x);
        f[4]  = sinf(1.0f * x); f[5]  = sinf(0.5f * x); f[6]  = sinf(F3 * x);
        f[7]  = cosf(1.0f * x); f[8]  = cosf(2.0f * x); f[9]  = cosf(3.0f * x);
        f[10] = cosf(1.0f * x); f[11] = cosf(0.5f * x); f[12] = cosf(F3 * x);
    }
    __syncthreads();

    // ---- layer 1: h1[r][t] = relu(b1 + aaT[seq] + chT[chain] + coord@W1c + dih@W1d) ----
    {
        float wd[40];
        #pragma unroll
        for (int k = 0; k < 40; ++k)            // row 1067 (k=39) multiplied by zero pad
            wd[k] = W1[(size_t)(ROW_DIH + k) * W1_N + t];
        const float bb = b1[t];

        for (int r = 0; r < TM; ++r) {
            const int sq = s_seq[r];
            const float* w1c = W1 + (size_t)(ROW_COORD + sq * 45) * W1_N + t;
            float acc = bb + aaT[sq * W1_N + t] + chT[s_chain[r] * W1_N + t];

            const float4* f4 = (const float4*)&feat[r][0];
            #pragma unroll
            for (int k4 = 0; k4 < 12; ++k4) {   // 48 coord slots (3 zero-padded)
                const float4 f = f4[k4];
                acc += f.x * w1c[(k4*4+0) * W1_N];
                acc += f.y * w1c[(k4*4+1) * W1_N];
                acc += f.z * w1c[(k4*4+2) * W1_N];
                acc += f.w * w1c[(k4*4+3) * W1_N];
            }
            const float4* fd4 = (const float4*)&feat[r][48];
            #pragma unroll
            for (int k4 = 0; k4 < 10; ++k4) {   // 40 dihedral slots (1 zero-padded)
                const float4 f = fd4[k4];
                acc += f.x * wd[k4*4+0];
                acc += f.y * wd[k4*4+1];
                acc += f.z * wd[k4*4+2];
                acc += f.w * wd[k4*4+3];
            }
            h1[r][t] = fmaxf(acc, 0.f);
        }
    }
    __syncthreads();

    const int rg = t >> 5;          // 0..7  -> rows r0..r0+3
    const int cg = t & 31;          // 0..31 -> cols j0..j0+3
    const int r0 = rg * 4, j0 = cg * 4;

    // ---- layer 2: h2 = relu(h1 @ W2 + b2), K=256, N=128 ----
    {
        const float4 bv = *(const float4*)&b2[j0];
        float4 c0 = bv, c1 = bv, c2 = bv, c3 = bv;
        for (int k = 0; k < 256; k += 4) {
            float a0v[4], a1v[4], a2v[4], a3v[4];
            *(float4*)a0v = *(const float4*)&h1[r0+0][k];
            *(float4*)a1v = *(const float4*)&h1[r0+1][k];
            *(float4*)a2v = *(const float4*)&h1[r0+2][k];
            *(float4*)a3v = *(const float4*)&h1[r0+3][k];
            #pragma unroll
            for (int kk = 0; kk < 4; ++kk) {
                const float4 w = *(const float4*)&W2[(size_t)(k+kk)*128 + j0];
                c0.x += a0v[kk]*w.x; c0.y += a0v[kk]*w.y; c0.z += a0v[kk]*w.z; c0.w += a0v[kk]*w.w;
                c1.x += a1v[kk]*w.x; c1.y += a1v[kk]*w.y; c1.z += a1v[kk]*w.z; c1.w += a1v[kk]*w.w;
                c2.x += a2v[kk]*w.x; c2.y += a2v[kk]*w.y; c2.z += a2v[kk]*w.z; c2.w += a2v[kk]*w.w;
                c3.x += a3v[kk]*w.x; c3.y += a3v[kk]*w.y; c3.z += a3v[kk]*w.z; c3.w += a3v[kk]*w.w;
            }
        }
        *(float4*)&h2[r0+0][j0] = relu4(c0);
        *(float4*)&h2[r0+1][j0] = relu4(c1);
        *(float4*)&h2[r0+2][j0] = relu4(c2);
        *(float4*)&h2[r0+3][j0] = relu4(c3);
    }
    __syncthreads();

    float (*h3)[128] = (float(*)[128])h1;   // h1 dead, reuse its LDS

    // ---- layer 3: h3 = relu(h2 @ W3 + b3), K=128, N=128 ----
    {
        const float4 bv = *(const float4*)&b3[j0];
        float4 c0 = bv, c1 = bv, c2 = bv, c3 = bv;
        for (int k = 0; k < 128; k += 4) {
            float a0v[4], a1v[4], a2v[4], a3v[4];
            *(float4*)a0v = *(const float4*)&h2[r0+0][k];
            *(float4*)a1v = *(const float4*)&h2[r0+1][k];
            *(float4*)a2v = *(const float4*)&h2[r0+2][k];
            *(float4*)a3v = *(const float4*)&h2[r0+3][k];
            #pragma unroll
            for (int kk = 0; kk < 4; ++kk) {
                const float4 w = *(const float4*)&W3[(size_t)(k+kk)*128 + j0];
                c0.x += a0v[kk]*w.x; c0.y += a0v[kk]*w.y; c0.z += a0v[kk]*w.z; c0.w += a0v[kk]*w.w;
                c1.x += a1v[kk]*w.x; c1.y += a1v[kk]*w.y; c1.z += a1v[kk]*w.z; c1.w += a1v[kk]*w.w;
                c2.x += a2v[kk]*w.x; c2.y += a2v[kk]*w.y; c2.z += a2v[kk]*w.z; c2.w += a2v[kk]*w.w;
                c3.x += a3v[kk]*w.x; c3.y += a3v[kk]*w.y; c3.z += a3v[kk]*w.z; c3.w += a3v[kk]*w.w;
            }
        }
        __syncthreads();   // everyone done reading h2 before... (h3 aliases h1, h2 still live for no one) -- safe: writes below go to h1 region
        *(float4*)&h3[r0+0][j0] = relu4(c0);
        *(float4*)&h3[r0+1][j0] = relu4(c1);
        *(float4*)&h3[r0+2][j0] = relu4(c2);
        *(float4*)&h3[r0+3][j0] = relu4(c3);
    }
    __syncthreads();

    // ---- layer 4: out = h3 @ W4 + b4 (no relu) ----
    {
        const float4 bv = *(const float4*)&b4[j0];
        float4 c0 = bv, c1 = bv, c2 = bv, c3 = bv;
        for (int k = 0; k < 128; k += 4) {
            float a0v[4], a1v[4], a2v[4], a3v[4];
            *(float4*)a0v = *(const float4*)&h3[r0+0][k];
            *(float4*)a1v = *(const float4*)&h3[r0+1][k];
            *(float4*)a2v = *(const float4*)&h3[r0+2][k];
            *(float4*)a3v = *(const float4*)&h3[r0+3][k];
            #pragma unroll
            for (int kk = 0; kk < 4; ++kk) {
                const float4 w = *(const float4*)&W4[(size_t)(k+kk)*128 + j0];
                c0.x += a0v[kk]*w.x; c0.y += a0v[kk]*w.y; c0.z += a0v[kk]*w.z; c0.w += a0v[kk]*w.w;
                c1.x += a1v[kk]*w.x; c1.y += a1v[kk]*w.y; c1.z += a1v[kk]*w.z; c1.w += a1v[kk]*w.w;
                c2.x += a2v[kk]*w.x; c2.y += a2v[kk]*w.y; c2.z += a2v[kk]*w.z; c2.w += a2v[kk]*w.w;
                c3.x += a3v[kk]*w.x; c3.y += a3v[kk]*w.y; c3.z += a3v[kk]*w.z; c3.w += a3v[kk]*w.w;
            }
        }
        *(float4*)&out[(size_t)(row0 + r0 + 0) * 128 + j0] = c0;
        *(float4*)&out[(size_t)(row0 + r0 + 1) * 128 + j0] = c1;
        *(float4*)&out[(size_t)(row0 + r0 + 2) * 128 + j0] = c2;
        *(float4*)&out[(size_t)(row0 + r0 + 3) * 128 + j0] = c3;
    }
}

extern "C" void kernel_launch(void* const* d_in, const int* in_sizes, int n_in,
                              void* d_out, int out_size, void* d_ws, size_t ws_size,
                              hipStream_t stream) {
    const int*   seq    = (const int*)d_in[0];
    const float* xyz    = (const float*)d_in[1];
    const float* dihed  = (const float*)d_in[2];
    const int*   chain  = (const int*)d_in[3];
    const float* orient = (const float*)d_in[4];
    // d_in[5] = atom_mask: unused by the reference
    const float* aa_emb = (const float*)d_in[6];
    const float* ch_emb = (const float*)d_in[7];
    const float* W1 = (const float*)d_in[8];
    const float* b1 = (const float*)d_in[9];
    const float* W2 = (const float*)d_in[10];
    const float* b2 = (const float*)d_in[11];
    const float* W3 = (const float*)d_in[12];
    const float* b3 = (const float*)d_in[13];
    const float* W4 = (const float*)d_in[14];
    const float* b4 = (const float*)d_in[15];
    float* out = (float*)d_out;

    float* aaT = (float*)d_ws;            // 20 x 256
    float* chT = aaT + N_AA * W1_N;       // 10 x 256

    const int BL = in_sizes[0];           // 16384 rows

    tables_kernel<<<N_AA + 10, 256, 0, stream>>>(aa_emb, ch_emb, W1, aaT, chT);
    fused_kernel<<<BL / TM, 256, 0, stream>>>(seq, xyz, dihed, chain, orient,
                                              W1, b1, W2, b2, W3, b3, W4, b4,
                                              aaT, chT, out);
}